// Round 4
// baseline (1153.633 us; speedup 1.0000x reference)
//
#include <hip/hip_runtime.h>
#include <math.h>

#define NQ 14
#define NL 6
#define NTHREADS 1024
#define NGATES (NL * NQ)
#define CHUNK 16            // amps per thread: amp = (tid<<4) | j
// amp bit p: p<4 local (register), 4<=p<10 lane bit (tid bit p-4),
//            p>=10 wave bit (tid bit p-4 in 6..9). Wire w <-> bit P = 13-w.

using F4 = float4;

// ---- prep: Rot matrices (batch-shared) into d_ws ----
// Rot(phi,theta,omega) = RZ(omega) RY(theta) RZ(phi)
__global__ void prep_kernel(const float* __restrict__ wts, float* __restrict__ gm) {
    int g = blockIdx.x * blockDim.x + threadIdx.x;
    if (g < NGATES) {
        float phi = wts[g*3+0], th = wts[g*3+1], om = wts[g*3+2];
        float c = cosf(0.5f*th), s = sinf(0.5f*th);
        float a = 0.5f*(phi+om), bb = 0.5f*(phi-om);
        float ca = cosf(a), sa = sinf(a);
        float cb = cosf(bb), sb = sinf(bb);
        gm[g*8+0] = c*ca;  gm[g*8+1] = -c*sa;   // m00
        gm[g*8+2] = -s*cb; gm[g*8+3] = -s*sb;   // m01
        gm[g*8+4] = s*cb;  gm[g*8+5] = -s*sb;   // m10
        gm[g*8+6] = c*ca;  gm[g*8+7] = c*sa;    // m11
    }
}

// ---- RX(t): [[c,-is],[-is,c]] (symmetric combine) ----
template<int P>
__device__ __forceinline__ void rx_gate(float (&ar)[CHUNK], float (&ai)[CHUNK],
                                        float c, float s, int tid, F4* buf) {
    if constexpr (P < 4) {
        constexpr int M = 1 << P;
        #pragma unroll
        for (int i = 0; i < CHUNK/2; ++i) {
            int j0 = ((i >> P) << (P+1)) | (i & (M-1));
            int j1 = j0 | M;
            float r0=ar[j0], i0=ai[j0], r1=ar[j1], i1=ai[j1];
            ar[j0] = c*r0 + s*i1;
            ai[j0] = c*i0 - s*r1;
            ar[j1] = s*i0 + c*r1;
            ai[j1] = -s*r0 + c*i1;
        }
    } else if constexpr (P < 10) {
        constexpr int LM = 1 << (P-4);
        #pragma unroll
        for (int j = 0; j < CHUNK; ++j) {
            float br = __shfl_xor(ar[j], LM, 64);
            float bi = __shfl_xor(ai[j], LM, 64);
            float nr = c*ar[j] + s*bi;
            float ni = c*ai[j] - s*br;
            ar[j] = nr; ai[j] = ni;
        }
    } else {
        constexpr int WM = 1 << (P-4);
        int ptid = tid ^ WM;
        #pragma unroll
        for (int k = 0; k < 4; ++k) {
            int j = 4*k;
            buf[k*NTHREADS + tid]     = make_float4(ar[j],ar[j+1],ar[j+2],ar[j+3]);
            buf[(k+4)*NTHREADS + tid] = make_float4(ai[j],ai[j+1],ai[j+2],ai[j+3]);
        }
        __syncthreads();
        #pragma unroll
        for (int k = 0; k < 4; ++k) {
            F4 pr = buf[k*NTHREADS + ptid];
            F4 pi = buf[(k+4)*NTHREADS + ptid];
            int j = 4*k;
            float prx[4] = {pr.x,pr.y,pr.z,pr.w};
            float pix[4] = {pi.x,pi.y,pi.z,pi.w};
            #pragma unroll
            for (int m = 0; m < 4; ++m) {
                float nr = c*ar[j+m] + s*pix[m];
                float ni = c*ai[j+m] - s*prx[m];
                ar[j+m] = nr; ai[j+m] = ni;
            }
        }
        __syncthreads();
    }
}

// ---- Rot: lo' = m00*lo + m01*hi; hi' = m10*lo + m11*hi ----
template<int P>
__device__ __forceinline__ void rot_gate(float (&ar)[CHUNK], float (&ai)[CHUNK],
                                         const float* __restrict__ m, int tid, F4* buf) {
    if constexpr (P < 4) {
        constexpr int M = 1 << P;
        float m0=m[0],m1=m[1],m2=m[2],m3=m[3],m4=m[4],m5=m[5],m6=m[6],m7=m[7];
        #pragma unroll
        for (int i = 0; i < CHUNK/2; ++i) {
            int j0 = ((i >> P) << (P+1)) | (i & (M-1));
            int j1 = j0 | M;
            float r0=ar[j0], i0=ai[j0], r1=ar[j1], i1=ai[j1];
            ar[j0] = m0*r0 - m1*i0 + m2*r1 - m3*i1;
            ai[j0] = m0*i0 + m1*r0 + m2*i1 + m3*r1;
            ar[j1] = m4*r0 - m5*i0 + m6*r1 - m7*i1;
            ai[j1] = m4*i0 + m5*r0 + m6*i1 + m7*r1;
        }
    } else if constexpr (P < 10) {
        constexpr int LM = 1 << (P-4);
        int bit = (tid >> (P-4)) & 1;
        float cAr = bit ? m[6] : m[0];
        float cAi = bit ? m[7] : m[1];
        float cBr = bit ? m[4] : m[2];
        float cBi = bit ? m[5] : m[3];
        #pragma unroll
        for (int j = 0; j < CHUNK; ++j) {
            float br = __shfl_xor(ar[j], LM, 64);
            float bi = __shfl_xor(ai[j], LM, 64);
            float nr = cAr*ar[j] - cAi*ai[j] + cBr*br - cBi*bi;
            float ni = cAr*ai[j] + cAi*ar[j] + cBr*bi + cBi*br;
            ar[j] = nr; ai[j] = ni;
        }
    } else {
        constexpr int WM = 1 << (P-4);
        int ptid = tid ^ WM;
        int bit = (tid >> (P-4)) & 1;
        float cAr = bit ? m[6] : m[0];
        float cAi = bit ? m[7] : m[1];
        float cBr = bit ? m[4] : m[2];
        float cBi = bit ? m[5] : m[3];
        #pragma unroll
        for (int k = 0; k < 4; ++k) {
            int j = 4*k;
            buf[k*NTHREADS + tid]     = make_float4(ar[j],ar[j+1],ar[j+2],ar[j+3]);
            buf[(k+4)*NTHREADS + tid] = make_float4(ai[j],ai[j+1],ai[j+2],ai[j+3]);
        }
        __syncthreads();
        #pragma unroll
        for (int k = 0; k < 4; ++k) {
            F4 pr = buf[k*NTHREADS + ptid];
            F4 pi = buf[(k+4)*NTHREADS + ptid];
            int j = 4*k;
            float prx[4] = {pr.x,pr.y,pr.z,pr.w};
            float pix[4] = {pi.x,pi.y,pi.z,pi.w};
            #pragma unroll
            for (int m = 0; m < 4; ++m) {
                float nr = cAr*ar[j+m] - cAi*ai[j+m] + cBr*prx[m] - cBi*pix[m];
                float ni = cAr*ai[j+m] + cAi*ar[j+m] + cBr*pix[m] + cBi*prx[m];
                ar[j+m] = nr; ai[j+m] = ni;
            }
        }
        __syncthreads();
    }
}

// ---- CNOT(ctrl bit PC, target bit PT) ----
template<int PC, int PT>
__device__ __forceinline__ void cnot_gate(float (&ar)[CHUNK], float (&ai)[CHUNK],
                                          int tid, F4* buf) {
    if constexpr (PT < 4) {
        constexpr int TM = 1 << PT;
        if constexpr (PC < 4) {
            constexpr int CM = 1 << PC;
            #pragma unroll
            for (int j = 0; j < CHUNK; ++j) {
                if ((j & CM) && !(j & TM)) {
                    int j1 = j | TM;
                    float t = ar[j]; ar[j] = ar[j1]; ar[j1] = t;
                    t = ai[j]; ai[j] = ai[j1]; ai[j1] = t;
                }
            }
        } else {
            int sel = (tid >> (PC-4)) & 1;
            #pragma unroll
            for (int i = 0; i < CHUNK/2; ++i) {
                int j0 = ((i >> PT) << (PT+1)) | (i & (TM-1));
                int j1 = j0 | TM;
                float a = ar[j0], bv = ar[j1];
                ar[j0] = sel ? bv : a; ar[j1] = sel ? a : bv;
                a = ai[j0]; bv = ai[j1];
                ai[j0] = sel ? bv : a; ai[j1] = sel ? a : bv;
            }
        }
    } else if constexpr (PT < 10) {
        constexpr int LM = 1 << (PT-4);
        if constexpr (PC < 4) {
            constexpr int CM = 1 << PC;
            #pragma unroll
            for (int j = 0; j < CHUNK; ++j) {
                if (j & CM) {
                    ar[j] = __shfl_xor(ar[j], LM, 64);
                    ai[j] = __shfl_xor(ai[j], LM, 64);
                }
            }
        } else {
            int sel = (tid >> (PC-4)) & 1;
            if (sel) {  // partner differs only in PT lane bit -> same sel
                #pragma unroll
                for (int j = 0; j < CHUNK; ++j) {
                    ar[j] = __shfl_xor(ar[j], LM, 64);
                    ai[j] = __shfl_xor(ai[j], LM, 64);
                }
            }
        }
    } else {
        constexpr int WM = 1 << (PT-4);
        int ptid = tid ^ WM;
        if constexpr (PC < 4) {
            constexpr int CM = 1 << PC;
            // exchange only the 8 ctrl==1 amps (half traffic)
            #pragma unroll
            for (int k = 0; k < 2; ++k) {
                float v[8];
                #pragma unroll
                for (int m = 0; m < 4; ++m) {
                    int i = 4*k + m;
                    int j = ((i >> PC) << (PC+1)) | (i & (CM-1)) | CM;
                    v[m] = ar[j]; v[4+m] = ai[j];
                }
                buf[k*NTHREADS + tid]     = make_float4(v[0],v[1],v[2],v[3]);
                buf[(k+2)*NTHREADS + tid] = make_float4(v[4],v[5],v[6],v[7]);
            }
            __syncthreads();
            #pragma unroll
            for (int k = 0; k < 2; ++k) {
                F4 pr = buf[k*NTHREADS + ptid];
                F4 pi = buf[(k+2)*NTHREADS + ptid];
                float prx[4] = {pr.x,pr.y,pr.z,pr.w};
                float pix[4] = {pi.x,pi.y,pi.z,pi.w};
                #pragma unroll
                for (int m = 0; m < 4; ++m) {
                    int i = 4*k + m;
                    int j = ((i >> PC) << (PC+1)) | (i & (CM-1)) | CM;
                    ar[j] = prx[m]; ai[j] = pix[m];
                }
            }
            __syncthreads();
        } else {
            // ctrl is a thread bit != PT: sel==1 threads swap whole chunk
            int sel = (tid >> (PC-4)) & 1;
            if (sel) {
                #pragma unroll
                for (int k = 0; k < 4; ++k) {
                    int j = 4*k;
                    buf[k*NTHREADS + tid]     = make_float4(ar[j],ar[j+1],ar[j+2],ar[j+3]);
                    buf[(k+4)*NTHREADS + tid] = make_float4(ai[j],ai[j+1],ai[j+2],ai[j+3]);
                }
            }
            __syncthreads();
            if (sel) {
                #pragma unroll
                for (int k = 0; k < 4; ++k) {
                    F4 pr = buf[k*NTHREADS + ptid];
                    F4 pi = buf[(k+4)*NTHREADS + ptid];
                    int j = 4*k;
                    ar[j]=pr.x; ar[j+1]=pr.y; ar[j+2]=pr.z; ar[j+3]=pr.w;
                    ai[j]=pi.x; ai[j+1]=pi.y; ai[j+2]=pi.z; ai[j+3]=pi.w;
                }
            }
            __syncthreads();
        }
    }
}

// ---- compile-time circuit drivers ----
template<int W>
__device__ __forceinline__ void do_rx(float (&ar)[CHUNK], float (&ai)[CHUNK],
                                      const float* __restrict__ xb, int tid, F4* buf) {
    float t = xb[W];
    float c = cosf(0.5f*t), s = sinf(0.5f*t);
    rx_gate<13-W>(ar, ai, c, s, tid, buf);
    if constexpr (W < NQ-1) do_rx<W+1>(ar, ai, xb, tid, buf);
}

template<int L, int W>
__device__ __forceinline__ void do_rots(float (&ar)[CHUNK], float (&ai)[CHUNK],
                                        const float* __restrict__ gm, int tid, F4* buf) {
    rot_gate<13-W>(ar, ai, gm + (L*NQ + W)*8, tid, buf);
    if constexpr (W < NQ-1) do_rots<L, W+1>(ar, ai, gm, tid, buf);
}

template<int L, int W>
__device__ __forceinline__ void do_cnots(float (&ar)[CHUNK], float (&ai)[CHUNK],
                                         int tid, F4* buf) {
    constexpr int R = (L % (NQ-1)) + 1;
    constexpr int TW = (W + R) % NQ;
    cnot_gate<13-W, 13-TW>(ar, ai, tid, buf);
    if constexpr (W < NQ-1) do_cnots<L, W+1>(ar, ai, tid, buf);
}

template<int L>
__device__ __forceinline__ void do_layer(float (&ar)[CHUNK], float (&ai)[CHUNK],
                                         const float* __restrict__ gm, int tid, F4* buf) {
    do_rots<L, 0>(ar, ai, gm, tid, buf);
    do_cnots<L, 0>(ar, ai, tid, buf);
    if constexpr (L < NL-1) do_layer<L+1>(ar, ai, gm, tid, buf);
}

// LDS (128 KB) caps us at 1 block/CU = 4 waves/SIMD; pin the register
// allocator to that occupancy so it uses the full 128-VGPR budget instead
// of spilling to hit an unreachable 8 waves/SIMD.
__global__ void __launch_bounds__(NTHREADS)
__attribute__((amdgpu_waves_per_eu(4, 4)))
qsim_kernel(
    const float* __restrict__ x,
    const float* __restrict__ gm,
    float* __restrict__ out)
{
    extern __shared__ F4 buf[];   // 8 * 1024 float4 = 128 KB exchange buffer
    const int tid = threadIdx.x;
    const int b = blockIdx.x;

    float ar[CHUNK], ai[CHUNK];
    #pragma unroll
    for (int j = 0; j < CHUNK; ++j) { ar[j] = 0.f; ai[j] = 0.f; }
    if (tid == 0) ar[0] = 1.f;

    do_rx<0>(ar, ai, x + b*NQ, tid, buf);
    do_layer<0>(ar, ai, gm, tid, buf);

    // <Z0>: amp bit 13 = tid bit 9 -> sign uniform per thread
    float acc = 0.f;
    #pragma unroll
    for (int j = 0; j < CHUNK; ++j) acc += ar[j]*ar[j] + ai[j]*ai[j];
    if (tid & 512) acc = -acc;
    #pragma unroll
    for (int off = 32; off > 0; off >>= 1) acc += __shfl_down(acc, off, 64);
    __syncthreads();
    float* f = (float*)buf;
    if ((tid & 63) == 0) f[tid >> 6] = acc;
    __syncthreads();
    if (tid == 0) {
        float s = 0.f;
        #pragma unroll
        for (int w = 0; w < NTHREADS/64; ++w) s += f[w];
        out[b] = s;
    }
}

extern "C" void kernel_launch(void* const* d_in, const int* in_sizes, int n_in,
                              void* d_out, int out_size, void* d_ws, size_t ws_size,
                              hipStream_t stream) {
    const float* x = (const float*)d_in[0];   // (1024, 14) float32
    const float* w = (const float*)d_in[1];   // (6, 14, 3) float32
    float* out = (float*)d_out;               // (1024,) float32
    float* gm = (float*)d_ws;                 // 84*8 floats of Rot matrices

    prep_kernel<<<1, 128, 0, stream>>>(w, gm);
    size_t smem = (size_t)8 * NTHREADS * sizeof(F4);  // 128 KB
    qsim_kernel<<<out_size, NTHREADS, smem, stream>>>(x, gm, out);
}

// Round 5
// 1087.402 us; speedup vs baseline: 1.0609x; 1.0609x over previous
//
#include <hip/hip_runtime.h>
#include <math.h>

#define NQ 14
#define NL 6
#define NTHREADS 1024
#define NGATES (NL * NQ)
#define CHUNK 16            // amps per thread: amp = (tid<<4) | j
// amp bit p: p<4 local (register), 4<=p<10 lane bit (tid bit p-4),
//            p>=10 wave bit (tid bit p-4 in 6..9). Wire w <-> bit P = 13-w.
// Wave-bit exchanges are done in 2 half-chunk phases (8 amps each) to keep
// peak register pressure < 64 VGPRs (the allocator's budget at 8 waves/SIMD)
// and to shrink the LDS exchange buffer to 64 KB -> 2 blocks/CU.

using F4 = float4;

// ---- prep: Rot matrices (batch-shared) into d_ws ----
// Rot(phi,theta,omega) = RZ(omega) RY(theta) RZ(phi)
__global__ void prep_kernel(const float* __restrict__ wts, float* __restrict__ gm) {
    int g = blockIdx.x * blockDim.x + threadIdx.x;
    if (g < NGATES) {
        float phi = wts[g*3+0], th = wts[g*3+1], om = wts[g*3+2];
        float c = cosf(0.5f*th), s = sinf(0.5f*th);
        float a = 0.5f*(phi+om), bb = 0.5f*(phi-om);
        float ca = cosf(a), sa = sinf(a);
        float cb = cosf(bb), sb = sinf(bb);
        gm[g*8+0] = c*ca;  gm[g*8+1] = -c*sa;   // m00
        gm[g*8+2] = -s*cb; gm[g*8+3] = -s*sb;   // m01
        gm[g*8+4] = s*cb;  gm[g*8+5] = -s*sb;   // m10
        gm[g*8+6] = c*ca;  gm[g*8+7] = c*sa;    // m11
    }
}

// ---- RX(t): [[c,-is],[-is,c]] (symmetric combine) ----
template<int P>
__device__ __forceinline__ void rx_gate(float (&ar)[CHUNK], float (&ai)[CHUNK],
                                        float c, float s, int tid, F4* buf) {
    if constexpr (P < 4) {
        constexpr int M = 1 << P;
        #pragma unroll
        for (int i = 0; i < CHUNK/2; ++i) {
            int j0 = ((i >> P) << (P+1)) | (i & (M-1));
            int j1 = j0 | M;
            float r0=ar[j0], i0=ai[j0], r1=ar[j1], i1=ai[j1];
            ar[j0] = c*r0 + s*i1;
            ai[j0] = c*i0 - s*r1;
            ar[j1] = s*i0 + c*r1;
            ai[j1] = -s*r0 + c*i1;
        }
    } else if constexpr (P < 10) {
        constexpr int LM = 1 << (P-4);
        #pragma unroll
        for (int j = 0; j < CHUNK; ++j) {
            float br = __shfl_xor(ar[j], LM, 64);
            float bi = __shfl_xor(ai[j], LM, 64);
            float nr = c*ar[j] + s*bi;
            float ni = c*ai[j] - s*br;
            ar[j] = nr; ai[j] = ni;
        }
    } else {
        constexpr int WM = 1 << (P-4);
        int ptid = tid ^ WM;
        #pragma unroll
        for (int h = 0; h < 2; ++h) {
            #pragma unroll
            for (int k = 0; k < 2; ++k) {
                int j = 8*h + 4*k;
                buf[k*NTHREADS + tid]     = make_float4(ar[j],ar[j+1],ar[j+2],ar[j+3]);
                buf[(k+2)*NTHREADS + tid] = make_float4(ai[j],ai[j+1],ai[j+2],ai[j+3]);
            }
            __syncthreads();
            #pragma unroll
            for (int k = 0; k < 2; ++k) {
                F4 pr = buf[k*NTHREADS + ptid];
                F4 pi = buf[(k+2)*NTHREADS + ptid];
                int j = 8*h + 4*k;
                float prx[4] = {pr.x,pr.y,pr.z,pr.w};
                float pix[4] = {pi.x,pi.y,pi.z,pi.w};
                #pragma unroll
                for (int m = 0; m < 4; ++m) {
                    float nr = c*ar[j+m] + s*pix[m];
                    float ni = c*ai[j+m] - s*prx[m];
                    ar[j+m] = nr; ai[j+m] = ni;
                }
            }
            __syncthreads();
        }
    }
}

// ---- Rot: lo' = m00*lo + m01*hi; hi' = m10*lo + m11*hi ----
template<int P>
__device__ __forceinline__ void rot_gate(float (&ar)[CHUNK], float (&ai)[CHUNK],
                                         const float* __restrict__ m, int tid, F4* buf) {
    if constexpr (P < 4) {
        constexpr int M = 1 << P;
        float m0=m[0],m1=m[1],m2=m[2],m3=m[3],m4=m[4],m5=m[5],m6=m[6],m7=m[7];
        #pragma unroll
        for (int i = 0; i < CHUNK/2; ++i) {
            int j0 = ((i >> P) << (P+1)) | (i & (M-1));
            int j1 = j0 | M;
            float r0=ar[j0], i0=ai[j0], r1=ar[j1], i1=ai[j1];
            ar[j0] = m0*r0 - m1*i0 + m2*r1 - m3*i1;
            ai[j0] = m0*i0 + m1*r0 + m2*i1 + m3*r1;
            ar[j1] = m4*r0 - m5*i0 + m6*r1 - m7*i1;
            ai[j1] = m4*i0 + m5*r0 + m6*i1 + m7*r1;
        }
    } else if constexpr (P < 10) {
        constexpr int LM = 1 << (P-4);
        int bit = (tid >> (P-4)) & 1;
        float cAr = bit ? m[6] : m[0];
        float cAi = bit ? m[7] : m[1];
        float cBr = bit ? m[4] : m[2];
        float cBi = bit ? m[5] : m[3];
        #pragma unroll
        for (int j = 0; j < CHUNK; ++j) {
            float br = __shfl_xor(ar[j], LM, 64);
            float bi = __shfl_xor(ai[j], LM, 64);
            float nr = cAr*ar[j] - cAi*ai[j] + cBr*br - cBi*bi;
            float ni = cAr*ai[j] + cAi*ar[j] + cBr*bi + cBi*br;
            ar[j] = nr; ai[j] = ni;
        }
    } else {
        constexpr int WM = 1 << (P-4);
        int ptid = tid ^ WM;
        int bit = (tid >> (P-4)) & 1;
        float cAr = bit ? m[6] : m[0];
        float cAi = bit ? m[7] : m[1];
        float cBr = bit ? m[4] : m[2];
        float cBi = bit ? m[5] : m[3];
        #pragma unroll
        for (int h = 0; h < 2; ++h) {
            #pragma unroll
            for (int k = 0; k < 2; ++k) {
                int j = 8*h + 4*k;
                buf[k*NTHREADS + tid]     = make_float4(ar[j],ar[j+1],ar[j+2],ar[j+3]);
                buf[(k+2)*NTHREADS + tid] = make_float4(ai[j],ai[j+1],ai[j+2],ai[j+3]);
            }
            __syncthreads();
            #pragma unroll
            for (int k = 0; k < 2; ++k) {
                F4 pr = buf[k*NTHREADS + ptid];
                F4 pi = buf[(k+2)*NTHREADS + ptid];
                int j = 8*h + 4*k;
                float prx[4] = {pr.x,pr.y,pr.z,pr.w};
                float pix[4] = {pi.x,pi.y,pi.z,pi.w};
                #pragma unroll
                for (int m = 0; m < 4; ++m) {
                    float nr = cAr*ar[j+m] - cAi*ai[j+m] + cBr*prx[m] - cBi*pix[m];
                    float ni = cAr*ai[j+m] + cAi*ar[j+m] + cBr*pix[m] + cBi*prx[m];
                    ar[j+m] = nr; ai[j+m] = ni;
                }
            }
            __syncthreads();
        }
    }
}

// ---- CNOT(ctrl bit PC, target bit PT) ----
template<int PC, int PT>
__device__ __forceinline__ void cnot_gate(float (&ar)[CHUNK], float (&ai)[CHUNK],
                                          int tid, F4* buf) {
    if constexpr (PT < 4) {
        constexpr int TM = 1 << PT;
        if constexpr (PC < 4) {
            constexpr int CM = 1 << PC;
            #pragma unroll
            for (int j = 0; j < CHUNK; ++j) {
                if ((j & CM) && !(j & TM)) {
                    int j1 = j | TM;
                    float t = ar[j]; ar[j] = ar[j1]; ar[j1] = t;
                    t = ai[j]; ai[j] = ai[j1]; ai[j1] = t;
                }
            }
        } else {
            int sel = (tid >> (PC-4)) & 1;
            #pragma unroll
            for (int i = 0; i < CHUNK/2; ++i) {
                int j0 = ((i >> PT) << (PT+1)) | (i & (TM-1));
                int j1 = j0 | TM;
                float a = ar[j0], bv = ar[j1];
                ar[j0] = sel ? bv : a; ar[j1] = sel ? a : bv;
                a = ai[j0]; bv = ai[j1];
                ai[j0] = sel ? bv : a; ai[j1] = sel ? a : bv;
            }
        }
    } else if constexpr (PT < 10) {
        constexpr int LM = 1 << (PT-4);
        if constexpr (PC < 4) {
            constexpr int CM = 1 << PC;
            #pragma unroll
            for (int j = 0; j < CHUNK; ++j) {
                if (j & CM) {
                    ar[j] = __shfl_xor(ar[j], LM, 64);
                    ai[j] = __shfl_xor(ai[j], LM, 64);
                }
            }
        } else {
            int sel = (tid >> (PC-4)) & 1;
            if (sel) {  // partner differs only in PT lane bit -> same sel
                #pragma unroll
                for (int j = 0; j < CHUNK; ++j) {
                    ar[j] = __shfl_xor(ar[j], LM, 64);
                    ai[j] = __shfl_xor(ai[j], LM, 64);
                }
            }
        }
    } else {
        constexpr int WM = 1 << (PT-4);
        int ptid = tid ^ WM;
        if constexpr (PC < 4) {
            constexpr int CM = 1 << PC;
            // exchange only the 8 ctrl==1 amps: fits one 4-slot phase
            #pragma unroll
            for (int k = 0; k < 2; ++k) {
                float v[8];
                #pragma unroll
                for (int m = 0; m < 4; ++m) {
                    int i = 4*k + m;
                    int j = ((i >> PC) << (PC+1)) | (i & (CM-1)) | CM;
                    v[m] = ar[j]; v[4+m] = ai[j];
                }
                buf[k*NTHREADS + tid]     = make_float4(v[0],v[1],v[2],v[3]);
                buf[(k+2)*NTHREADS + tid] = make_float4(v[4],v[5],v[6],v[7]);
            }
            __syncthreads();
            #pragma unroll
            for (int k = 0; k < 2; ++k) {
                F4 pr = buf[k*NTHREADS + ptid];
                F4 pi = buf[(k+2)*NTHREADS + ptid];
                float prx[4] = {pr.x,pr.y,pr.z,pr.w};
                float pix[4] = {pi.x,pi.y,pi.z,pi.w};
                #pragma unroll
                for (int m = 0; m < 4; ++m) {
                    int i = 4*k + m;
                    int j = ((i >> PC) << (PC+1)) | (i & (CM-1)) | CM;
                    ar[j] = prx[m]; ai[j] = pix[m];
                }
            }
            __syncthreads();
        } else {
            // ctrl is a thread bit != PT: sel==1 threads swap whole chunk,
            // in 2 half phases
            int sel = (tid >> (PC-4)) & 1;
            #pragma unroll
            for (int h = 0; h < 2; ++h) {
                if (sel) {
                    #pragma unroll
                    for (int k = 0; k < 2; ++k) {
                        int j = 8*h + 4*k;
                        buf[k*NTHREADS + tid]     = make_float4(ar[j],ar[j+1],ar[j+2],ar[j+3]);
                        buf[(k+2)*NTHREADS + tid] = make_float4(ai[j],ai[j+1],ai[j+2],ai[j+3]);
                    }
                }
                __syncthreads();
                if (sel) {
                    #pragma unroll
                    for (int k = 0; k < 2; ++k) {
                        F4 pr = buf[k*NTHREADS + ptid];
                        F4 pi = buf[(k+2)*NTHREADS + ptid];
                        int j = 8*h + 4*k;
                        ar[j]=pr.x; ar[j+1]=pr.y; ar[j+2]=pr.z; ar[j+3]=pr.w;
                        ai[j]=pi.x; ai[j+1]=pi.y; ai[j+2]=pi.z; ai[j+3]=pi.w;
                    }
                }
                __syncthreads();
            }
        }
    }
}

// ---- compile-time circuit drivers ----
template<int W>
__device__ __forceinline__ void do_rx(float (&ar)[CHUNK], float (&ai)[CHUNK],
                                      const float* __restrict__ xb, int tid, F4* buf) {
    float t = xb[W];
    float c = cosf(0.5f*t), s = sinf(0.5f*t);
    rx_gate<13-W>(ar, ai, c, s, tid, buf);
    if constexpr (W < NQ-1) do_rx<W+1>(ar, ai, xb, tid, buf);
}

template<int L, int W>
__device__ __forceinline__ void do_rots(float (&ar)[CHUNK], float (&ai)[CHUNK],
                                        const float* __restrict__ gm, int tid, F4* buf) {
    rot_gate<13-W>(ar, ai, gm + (L*NQ + W)*8, tid, buf);
    if constexpr (W < NQ-1) do_rots<L, W+1>(ar, ai, gm, tid, buf);
}

template<int L, int W>
__device__ __forceinline__ void do_cnots(float (&ar)[CHUNK], float (&ai)[CHUNK],
                                         int tid, F4* buf) {
    constexpr int R = (L % (NQ-1)) + 1;
    constexpr int TW = (W + R) % NQ;
    cnot_gate<13-W, 13-TW>(ar, ai, tid, buf);
    if constexpr (W < NQ-1) do_cnots<L, W+1>(ar, ai, tid, buf);
}

template<int L>
__device__ __forceinline__ void do_layer(float (&ar)[CHUNK], float (&ai)[CHUNK],
                                         const float* __restrict__ gm, int tid, F4* buf) {
    do_rots<L, 0>(ar, ai, gm, tid, buf);
    do_cnots<L, 0>(ar, ai, tid, buf);
    if constexpr (L < NL-1) do_layer<L+1>(ar, ai, gm, tid, buf);
}

__global__ void __launch_bounds__(NTHREADS)
qsim_kernel(
    const float* __restrict__ x,
    const float* __restrict__ gm,
    float* __restrict__ out)
{
    extern __shared__ F4 buf[];   // 4 * 1024 float4 = 64 KB -> 2 blocks/CU
    const int tid = threadIdx.x;
    const int b = blockIdx.x;

    float ar[CHUNK], ai[CHUNK];
    #pragma unroll
    for (int j = 0; j < CHUNK; ++j) { ar[j] = 0.f; ai[j] = 0.f; }
    if (tid == 0) ar[0] = 1.f;

    do_rx<0>(ar, ai, x + b*NQ, tid, buf);
    do_layer<0>(ar, ai, gm, tid, buf);

    // <Z0>: amp bit 13 = tid bit 9 -> sign uniform per thread
    float acc = 0.f;
    #pragma unroll
    for (int j = 0; j < CHUNK; ++j) acc += ar[j]*ar[j] + ai[j]*ai[j];
    if (tid & 512) acc = -acc;
    #pragma unroll
    for (int off = 32; off > 0; off >>= 1) acc += __shfl_down(acc, off, 64);
    __syncthreads();
    float* f = (float*)buf;
    if ((tid & 63) == 0) f[tid >> 6] = acc;
    __syncthreads();
    if (tid == 0) {
        float s = 0.f;
        #pragma unroll
        for (int w = 0; w < NTHREADS/64; ++w) s += f[w];
        out[b] = s;
    }
}

extern "C" void kernel_launch(void* const* d_in, const int* in_sizes, int n_in,
                              void* d_out, int out_size, void* d_ws, size_t ws_size,
                              hipStream_t stream) {
    const float* x = (const float*)d_in[0];   // (1024, 14) float32
    const float* w = (const float*)d_in[1];   // (6, 14, 3) float32
    float* out = (float*)d_out;               // (1024,) float32
    float* gm = (float*)d_ws;                 // 84*8 floats of Rot matrices

    prep_kernel<<<1, 128, 0, stream>>>(w, gm);
    size_t smem = (size_t)4 * NTHREADS * sizeof(F4);  // 64 KB
    qsim_kernel<<<out_size, NTHREADS, smem, stream>>>(x, gm, out);
}

// Round 6
// 1081.391 us; speedup vs baseline: 1.0668x; 1.0056x over previous
//
#include <hip/hip_runtime.h>
#include <math.h>

#define NQ 14
#define NL 6
#define NTHREADS 1024
#define NGATES (NL * NQ)
#define CHUNK 16            // amps per thread: amp = (tid<<4) | j
// amp bit p: p<4 local (register), 4<=p<10 lane bit (tid bit p-4),
//            p>=10 wave bit (tid bit p-4 in 6..9). Wire w <-> bit P = 13-w.
// STATIC 128 KB LDS: makes 1-block/CU visible to the compiler so the VGPR
// budget is 128 (4 waves/SIMD), which fits the ~90-VGPR demand -> no spill.

using F4 = float4;

// ---- prep: Rot matrices (batch-shared) into d_ws ----
// Rot(phi,theta,omega) = RZ(omega) RY(theta) RZ(phi)
__global__ void prep_kernel(const float* __restrict__ wts, float* __restrict__ gm) {
    int g = blockIdx.x * blockDim.x + threadIdx.x;
    if (g < NGATES) {
        float phi = wts[g*3+0], th = wts[g*3+1], om = wts[g*3+2];
        float c = cosf(0.5f*th), s = sinf(0.5f*th);
        float a = 0.5f*(phi+om), bb = 0.5f*(phi-om);
        float ca = cosf(a), sa = sinf(a);
        float cb = cosf(bb), sb = sinf(bb);
        gm[g*8+0] = c*ca;  gm[g*8+1] = -c*sa;   // m00
        gm[g*8+2] = -s*cb; gm[g*8+3] = -s*sb;   // m01
        gm[g*8+4] = s*cb;  gm[g*8+5] = -s*sb;   // m10
        gm[g*8+6] = c*ca;  gm[g*8+7] = c*sa;    // m11
    }
}

// ---- Rot: lo' = m00*lo + m01*hi; hi' = m10*lo + m11*hi ----
template<int P>
__device__ __forceinline__ void rot_gate(float (&ar)[CHUNK], float (&ai)[CHUNK],
                                         const float* __restrict__ m, int tid, F4* buf) {
    if constexpr (P < 4) {
        constexpr int M = 1 << P;
        float m0=m[0],m1=m[1],m2=m[2],m3=m[3],m4=m[4],m5=m[5],m6=m[6],m7=m[7];
        #pragma unroll
        for (int i = 0; i < CHUNK/2; ++i) {
            int j0 = ((i >> P) << (P+1)) | (i & (M-1));
            int j1 = j0 | M;
            float r0=ar[j0], i0=ai[j0], r1=ar[j1], i1=ai[j1];
            ar[j0] = m0*r0 - m1*i0 + m2*r1 - m3*i1;
            ai[j0] = m0*i0 + m1*r0 + m2*i1 + m3*r1;
            ar[j1] = m4*r0 - m5*i0 + m6*r1 - m7*i1;
            ai[j1] = m4*i0 + m5*r0 + m6*i1 + m7*r1;
        }
    } else if constexpr (P < 10) {
        constexpr int LM = 1 << (P-4);
        int bit = (tid >> (P-4)) & 1;
        float cAr = bit ? m[6] : m[0];
        float cAi = bit ? m[7] : m[1];
        float cBr = bit ? m[4] : m[2];
        float cBi = bit ? m[5] : m[3];
        #pragma unroll
        for (int j = 0; j < CHUNK; ++j) {
            float br = __shfl_xor(ar[j], LM, 64);
            float bi = __shfl_xor(ai[j], LM, 64);
            float nr = cAr*ar[j] - cAi*ai[j] + cBr*br - cBi*bi;
            float ni = cAr*ai[j] + cAi*ar[j] + cBr*bi + cBi*br;
            ar[j] = nr; ai[j] = ni;
        }
    } else {
        constexpr int WM = 1 << (P-4);
        int ptid = tid ^ WM;
        int bit = (tid >> (P-4)) & 1;
        float cAr = bit ? m[6] : m[0];
        float cAi = bit ? m[7] : m[1];
        float cBr = bit ? m[4] : m[2];
        float cBi = bit ? m[5] : m[3];
        #pragma unroll
        for (int k = 0; k < 4; ++k) {
            int j = 4*k;
            buf[k*NTHREADS + tid]     = make_float4(ar[j],ar[j+1],ar[j+2],ar[j+3]);
            buf[(k+4)*NTHREADS + tid] = make_float4(ai[j],ai[j+1],ai[j+2],ai[j+3]);
        }
        __syncthreads();
        #pragma unroll
        for (int k = 0; k < 4; ++k) {
            F4 pr = buf[k*NTHREADS + ptid];
            F4 pi = buf[(k+4)*NTHREADS + ptid];
            int j = 4*k;
            float prx[4] = {pr.x,pr.y,pr.z,pr.w};
            float pix[4] = {pi.x,pi.y,pi.z,pi.w};
            #pragma unroll
            for (int m2_ = 0; m2_ < 4; ++m2_) {
                float nr = cAr*ar[j+m2_] - cAi*ai[j+m2_] + cBr*prx[m2_] - cBi*pix[m2_];
                float ni = cAr*ai[j+m2_] + cAi*ar[j+m2_] + cBr*pix[m2_] + cBi*prx[m2_];
                ar[j+m2_] = nr; ai[j+m2_] = ni;
            }
        }
        __syncthreads();
    }
}

// ---- CNOT(ctrl bit PC, target bit PT) ----
template<int PC, int PT>
__device__ __forceinline__ void cnot_gate(float (&ar)[CHUNK], float (&ai)[CHUNK],
                                          int tid, F4* buf) {
    if constexpr (PT < 4) {
        constexpr int TM = 1 << PT;
        if constexpr (PC < 4) {
            constexpr int CM = 1 << PC;
            #pragma unroll
            for (int j = 0; j < CHUNK; ++j) {
                if ((j & CM) && !(j & TM)) {
                    int j1 = j | TM;
                    float t = ar[j]; ar[j] = ar[j1]; ar[j1] = t;
                    t = ai[j]; ai[j] = ai[j1]; ai[j1] = t;
                }
            }
        } else {
            int sel = (tid >> (PC-4)) & 1;
            #pragma unroll
            for (int i = 0; i < CHUNK/2; ++i) {
                int j0 = ((i >> PT) << (PT+1)) | (i & (TM-1));
                int j1 = j0 | TM;
                float a = ar[j0], bv = ar[j1];
                ar[j0] = sel ? bv : a; ar[j1] = sel ? a : bv;
                a = ai[j0]; bv = ai[j1];
                ai[j0] = sel ? bv : a; ai[j1] = sel ? a : bv;
            }
        }
    } else if constexpr (PT < 10) {
        constexpr int LM = 1 << (PT-4);
        if constexpr (PC < 4) {
            constexpr int CM = 1 << PC;
            #pragma unroll
            for (int j = 0; j < CHUNK; ++j) {
                if (j & CM) {
                    ar[j] = __shfl_xor(ar[j], LM, 64);
                    ai[j] = __shfl_xor(ai[j], LM, 64);
                }
            }
        } else {
            int sel = (tid >> (PC-4)) & 1;
            if (sel) {  // partner differs only in PT lane bit -> same sel
                #pragma unroll
                for (int j = 0; j < CHUNK; ++j) {
                    ar[j] = __shfl_xor(ar[j], LM, 64);
                    ai[j] = __shfl_xor(ai[j], LM, 64);
                }
            }
        }
    } else {
        constexpr int WM = 1 << (PT-4);
        int ptid = tid ^ WM;
        if constexpr (PC < 4) {
            constexpr int CM = 1 << PC;
            // exchange only the 8 ctrl==1 amps (half traffic)
            #pragma unroll
            for (int k = 0; k < 2; ++k) {
                float v[8];
                #pragma unroll
                for (int m = 0; m < 4; ++m) {
                    int i = 4*k + m;
                    int j = ((i >> PC) << (PC+1)) | (i & (CM-1)) | CM;
                    v[m] = ar[j]; v[4+m] = ai[j];
                }
                buf[k*NTHREADS + tid]     = make_float4(v[0],v[1],v[2],v[3]);
                buf[(k+2)*NTHREADS + tid] = make_float4(v[4],v[5],v[6],v[7]);
            }
            __syncthreads();
            #pragma unroll
            for (int k = 0; k < 2; ++k) {
                F4 pr = buf[k*NTHREADS + ptid];
                F4 pi = buf[(k+2)*NTHREADS + ptid];
                float prx[4] = {pr.x,pr.y,pr.z,pr.w};
                float pix[4] = {pi.x,pi.y,pi.z,pi.w};
                #pragma unroll
                for (int m = 0; m < 4; ++m) {
                    int i = 4*k + m;
                    int j = ((i >> PC) << (PC+1)) | (i & (CM-1)) | CM;
                    ar[j] = prx[m]; ai[j] = pix[m];
                }
            }
            __syncthreads();
        } else {
            // ctrl is a thread bit != PT: sel==1 threads swap whole chunk
            int sel = (tid >> (PC-4)) & 1;
            if (sel) {
                #pragma unroll
                for (int k = 0; k < 4; ++k) {
                    int j = 4*k;
                    buf[k*NTHREADS + tid]     = make_float4(ar[j],ar[j+1],ar[j+2],ar[j+3]);
                    buf[(k+4)*NTHREADS + tid] = make_float4(ai[j],ai[j+1],ai[j+2],ai[j+3]);
                }
            }
            __syncthreads();
            if (sel) {
                #pragma unroll
                for (int k = 0; k < 4; ++k) {
                    F4 pr = buf[k*NTHREADS + ptid];
                    F4 pi = buf[(k+4)*NTHREADS + ptid];
                    int j = 4*k;
                    ar[j]=pr.x; ar[j+1]=pr.y; ar[j+2]=pr.z; ar[j+3]=pr.w;
                    ai[j]=pi.x; ai[j+1]=pi.y; ai[j+2]=pi.z; ai[j+3]=pi.w;
                }
            }
            __syncthreads();
        }
    }
}

// ---- compile-time circuit drivers ----
template<int L, int W>
__device__ __forceinline__ void do_rots(float (&ar)[CHUNK], float (&ai)[CHUNK],
                                        const float* __restrict__ gm, int tid, F4* buf) {
    rot_gate<13-W>(ar, ai, gm + (L*NQ + W)*8, tid, buf);
    if constexpr (W < NQ-1) do_rots<L, W+1>(ar, ai, gm, tid, buf);
}

template<int L, int W>
__device__ __forceinline__ void do_cnots(float (&ar)[CHUNK], float (&ai)[CHUNK],
                                         int tid, F4* buf) {
    constexpr int R = (L % (NQ-1)) + 1;
    constexpr int TW = (W + R) % NQ;
    cnot_gate<13-W, 13-TW>(ar, ai, tid, buf);
    if constexpr (W < NQ-1) do_cnots<L, W+1>(ar, ai, tid, buf);
}

template<int L>
__device__ __forceinline__ void do_layer(float (&ar)[CHUNK], float (&ai)[CHUNK],
                                         const float* __restrict__ gm, int tid, F4* buf) {
    do_rots<L, 0>(ar, ai, gm, tid, buf);
    do_cnots<L, 0>(ar, ai, tid, buf);
    if constexpr (L < NL-1) do_layer<L+1>(ar, ai, gm, tid, buf);
}

__global__ void __launch_bounds__(NTHREADS)
qsim_kernel(
    const float* __restrict__ x,
    const float* __restrict__ gm,
    float* __restrict__ out)
{
    // STATIC 128 KB exchange buffer: compiler sees 1 block/CU -> VGPR budget 128
    __shared__ F4 buf[8 * NTHREADS];
    const int tid = threadIdx.x;
    const int b = blockIdx.x;
    const float* xb = x + b * NQ;

    // ---- direct product-state init: state after RX(x_w) on |0..0> ----
    // amp(p) = prod_b [ bit_b(p) ? -i*sin(x_{13-b}/2) : cos(x_{13-b}/2) ]
    float ar[CHUNK], ai[CHUNK];
    {
        // thread-common factor over tid bits (storage bits 4..13, wire 9-bb)
        float cr = 1.f, ci = 0.f;
        #pragma unroll
        for (int bb = 0; bb < 10; ++bb) {
            float t = xb[9 - bb];
            float c = cosf(0.5f*t), s = sinf(0.5f*t);
            if ((tid >> bb) & 1) { float nr = s*ci, ni = -s*cr; cr = nr; ci = ni; }
            else                 { cr *= c; ci *= c; }
        }
        // local bits 0..3 (wire 13-bb)
        float lc[4], ls[4];
        #pragma unroll
        for (int bb = 0; bb < 4; ++bb) {
            float t = xb[13 - bb];
            lc[bb] = cosf(0.5f*t); ls[bb] = sinf(0.5f*t);
        }
        #pragma unroll
        for (int j = 0; j < CHUNK; ++j) {
            float rr = cr, ii = ci;
            #pragma unroll
            for (int bb = 0; bb < 4; ++bb) {
                if ((j >> bb) & 1) { float nr = ls[bb]*ii, ni = -ls[bb]*rr; rr = nr; ii = ni; }
                else               { rr *= lc[bb]; ii *= lc[bb]; }
            }
            ar[j] = rr; ai[j] = ii;
        }
    }
    __syncthreads();

    do_layer<0>(ar, ai, gm, tid, buf);

    // <Z0>: amp bit 13 = tid bit 9 -> sign uniform per thread
    float acc = 0.f;
    #pragma unroll
    for (int j = 0; j < CHUNK; ++j) acc += ar[j]*ar[j] + ai[j]*ai[j];
    if (tid & 512) acc = -acc;
    #pragma unroll
    for (int off = 32; off > 0; off >>= 1) acc += __shfl_down(acc, off, 64);
    __syncthreads();
    float* f = (float*)buf;
    if ((tid & 63) == 0) f[tid >> 6] = acc;
    __syncthreads();
    if (tid == 0) {
        float s = 0.f;
        #pragma unroll
        for (int w = 0; w < NTHREADS/64; ++w) s += f[w];
        out[b] = s;
    }
}

extern "C" void kernel_launch(void* const* d_in, const int* in_sizes, int n_in,
                              void* d_out, int out_size, void* d_ws, size_t ws_size,
                              hipStream_t stream) {
    const float* x = (const float*)d_in[0];   // (1024, 14) float32
    const float* w = (const float*)d_in[1];   // (6, 14, 3) float32
    float* out = (float*)d_out;               // (1024,) float32
    float* gm = (float*)d_ws;                 // 84*8 floats of Rot matrices

    prep_kernel<<<1, 128, 0, stream>>>(w, gm);
    qsim_kernel<<<out_size, NTHREADS, 0, stream>>>(x, gm, out);
}

// Round 7
// 1004.031 us; speedup vs baseline: 1.1490x; 1.0770x over previous
//
#include <hip/hip_runtime.h>
#include <math.h>

#define NQ 14
#define NL 6
#define NT 512
#define NGATES (NL * NQ)
#define CHUNK 32            // amps per thread: amp = (tid<<5) | j
// amp bit p: p<5 local (register j bit p), 5<=p<11 lane bit (tid bit p-5),
//            p>=11 wave bit (tid bit p-5, i.e. tid bits 6..8).
// Wire w <-> amp bit P = 13-w.
// 512 threads + static 64 KB LDS: compiler sees 2 workgroups/CU -> 4 waves/SIMD
// -> 128-VGPR budget, which holds the 64-reg state + exchange temps (no spill).
// Wave-bit exchanges run in 2 half-chunk phases (16 amps each).

using F4 = float4;

// ---- prep: Rot matrices (batch-shared) into d_ws ----
// Rot(phi,theta,omega) = RZ(omega) RY(theta) RZ(phi)
__global__ void prep_kernel(const float* __restrict__ wts, float* __restrict__ gm) {
    int g = blockIdx.x * blockDim.x + threadIdx.x;
    if (g < NGATES) {
        float phi = wts[g*3+0], th = wts[g*3+1], om = wts[g*3+2];
        float c = cosf(0.5f*th), s = sinf(0.5f*th);
        float a = 0.5f*(phi+om), bb = 0.5f*(phi-om);
        float ca = cosf(a), sa = sinf(a);
        float cb = cosf(bb), sb = sinf(bb);
        gm[g*8+0] = c*ca;  gm[g*8+1] = -c*sa;   // m00
        gm[g*8+2] = -s*cb; gm[g*8+3] = -s*sb;   // m01
        gm[g*8+4] = s*cb;  gm[g*8+5] = -s*sb;   // m10
        gm[g*8+6] = c*ca;  gm[g*8+7] = c*sa;    // m11
    }
}

// ---- Rot: lo' = m00*lo + m01*hi; hi' = m10*lo + m11*hi ----
template<int P>
__device__ __forceinline__ void rot_gate(float (&ar)[CHUNK], float (&ai)[CHUNK],
                                         const float* __restrict__ m, int tid, F4* buf) {
    if constexpr (P < 5) {
        constexpr int M = 1 << P;
        float m0=m[0],m1=m[1],m2=m[2],m3=m[3],m4=m[4],m5=m[5],m6=m[6],m7=m[7];
        #pragma unroll
        for (int i = 0; i < CHUNK/2; ++i) {
            int j0 = ((i >> P) << (P+1)) | (i & (M-1));
            int j1 = j0 | M;
            float r0=ar[j0], i0=ai[j0], r1=ar[j1], i1=ai[j1];
            ar[j0] = m0*r0 - m1*i0 + m2*r1 - m3*i1;
            ai[j0] = m0*i0 + m1*r0 + m2*i1 + m3*r1;
            ar[j1] = m4*r0 - m5*i0 + m6*r1 - m7*i1;
            ai[j1] = m4*i0 + m5*r0 + m6*i1 + m7*r1;
        }
    } else if constexpr (P < 11) {
        constexpr int LM = 1 << (P-5);
        int bit = (tid >> (P-5)) & 1;
        float cAr = bit ? m[6] : m[0];
        float cAi = bit ? m[7] : m[1];
        float cBr = bit ? m[4] : m[2];
        float cBi = bit ? m[5] : m[3];
        #pragma unroll
        for (int j = 0; j < CHUNK; ++j) {
            float br = __shfl_xor(ar[j], LM, 64);
            float bi = __shfl_xor(ai[j], LM, 64);
            float nr = cAr*ar[j] - cAi*ai[j] + cBr*br - cBi*bi;
            float ni = cAr*ai[j] + cAi*ar[j] + cBr*bi + cBi*br;
            ar[j] = nr; ai[j] = ni;
        }
    } else {
        constexpr int WM = 1 << (P-5);
        int ptid = tid ^ WM;
        int bit = (tid >> (P-5)) & 1;
        float cAr = bit ? m[6] : m[0];
        float cAi = bit ? m[7] : m[1];
        float cBr = bit ? m[4] : m[2];
        float cBi = bit ? m[5] : m[3];
        #pragma unroll
        for (int h = 0; h < 2; ++h) {
            #pragma unroll
            for (int k = 0; k < 4; ++k) {
                int j = 16*h + 4*k;
                buf[k*NT + tid]     = make_float4(ar[j],ar[j+1],ar[j+2],ar[j+3]);
                buf[(k+4)*NT + tid] = make_float4(ai[j],ai[j+1],ai[j+2],ai[j+3]);
            }
            __syncthreads();
            #pragma unroll
            for (int k = 0; k < 4; ++k) {
                F4 pr = buf[k*NT + ptid];
                F4 pi = buf[(k+4)*NT + ptid];
                int j = 16*h + 4*k;
                float prx[4] = {pr.x,pr.y,pr.z,pr.w};
                float pix[4] = {pi.x,pi.y,pi.z,pi.w};
                #pragma unroll
                for (int q = 0; q < 4; ++q) {
                    float nr = cAr*ar[j+q] - cAi*ai[j+q] + cBr*prx[q] - cBi*pix[q];
                    float ni = cAr*ai[j+q] + cAi*ar[j+q] + cBr*pix[q] + cBi*prx[q];
                    ar[j+q] = nr; ai[j+q] = ni;
                }
            }
            __syncthreads();
        }
    }
}

// ---- CNOT(ctrl bit PC, target bit PT) ----
template<int PC, int PT>
__device__ __forceinline__ void cnot_gate(float (&ar)[CHUNK], float (&ai)[CHUNK],
                                          int tid, F4* buf) {
    if constexpr (PT < 5) {
        constexpr int TM = 1 << PT;
        if constexpr (PC < 5) {
            constexpr int CM = 1 << PC;
            #pragma unroll
            for (int j = 0; j < CHUNK; ++j) {
                if ((j & CM) && !(j & TM)) {
                    int j1 = j | TM;
                    float t = ar[j]; ar[j] = ar[j1]; ar[j1] = t;
                    t = ai[j]; ai[j] = ai[j1]; ai[j1] = t;
                }
            }
        } else {
            int sel = (tid >> (PC-5)) & 1;
            #pragma unroll
            for (int i = 0; i < CHUNK/2; ++i) {
                int j0 = ((i >> PT) << (PT+1)) | (i & (TM-1));
                int j1 = j0 | TM;
                float a = ar[j0], bv = ar[j1];
                ar[j0] = sel ? bv : a; ar[j1] = sel ? a : bv;
                a = ai[j0]; bv = ai[j1];
                ai[j0] = sel ? bv : a; ai[j1] = sel ? a : bv;
            }
        }
    } else if constexpr (PT < 11) {
        constexpr int LM = 1 << (PT-5);
        if constexpr (PC < 5) {
            constexpr int CM = 1 << PC;
            #pragma unroll
            for (int j = 0; j < CHUNK; ++j) {
                if (j & CM) {
                    ar[j] = __shfl_xor(ar[j], LM, 64);
                    ai[j] = __shfl_xor(ai[j], LM, 64);
                }
            }
        } else {
            int sel = (tid >> (PC-5)) & 1;
            if (sel) {  // partner differs only in PT lane bit -> same sel
                #pragma unroll
                for (int j = 0; j < CHUNK; ++j) {
                    ar[j] = __shfl_xor(ar[j], LM, 64);
                    ai[j] = __shfl_xor(ai[j], LM, 64);
                }
            }
        }
    } else {
        constexpr int WM = 1 << (PT-5);
        int ptid = tid ^ WM;
        if constexpr (PC < 5) {
            constexpr int CM = 1 << PC;
            // exchange only the 16 ctrl==1 amps: one phase (4+4 F4)
            #pragma unroll
            for (int k = 0; k < 4; ++k) {
                float v[8];
                #pragma unroll
                for (int q = 0; q < 4; ++q) {
                    int i = 4*k + q;
                    int j = ((i >> PC) << (PC+1)) | (i & (CM-1)) | CM;
                    v[q] = ar[j]; v[4+q] = ai[j];
                }
                buf[k*NT + tid]     = make_float4(v[0],v[1],v[2],v[3]);
                buf[(k+4)*NT + tid] = make_float4(v[4],v[5],v[6],v[7]);
            }
            __syncthreads();
            #pragma unroll
            for (int k = 0; k < 4; ++k) {
                F4 pr = buf[k*NT + ptid];
                F4 pi = buf[(k+4)*NT + ptid];
                float prx[4] = {pr.x,pr.y,pr.z,pr.w};
                float pix[4] = {pi.x,pi.y,pi.z,pi.w};
                #pragma unroll
                for (int q = 0; q < 4; ++q) {
                    int i = 4*k + q;
                    int j = ((i >> PC) << (PC+1)) | (i & (CM-1)) | CM;
                    ar[j] = prx[q]; ai[j] = pix[q];
                }
            }
            __syncthreads();
        } else {
            // ctrl is a thread bit != PT: sel==1 threads swap whole chunk,
            // in 2 half phases
            int sel = (tid >> (PC-5)) & 1;
            #pragma unroll
            for (int h = 0; h < 2; ++h) {
                if (sel) {
                    #pragma unroll
                    for (int k = 0; k < 4; ++k) {
                        int j = 16*h + 4*k;
                        buf[k*NT + tid]     = make_float4(ar[j],ar[j+1],ar[j+2],ar[j+3]);
                        buf[(k+4)*NT + tid] = make_float4(ai[j],ai[j+1],ai[j+2],ai[j+3]);
                    }
                }
                __syncthreads();
                if (sel) {
                    #pragma unroll
                    for (int k = 0; k < 4; ++k) {
                        F4 pr = buf[k*NT + ptid];
                        F4 pi = buf[(k+4)*NT + ptid];
                        int j = 16*h + 4*k;
                        ar[j]=pr.x; ar[j+1]=pr.y; ar[j+2]=pr.z; ar[j+3]=pr.w;
                        ai[j]=pi.x; ai[j+1]=pi.y; ai[j+2]=pi.z; ai[j+3]=pi.w;
                    }
                }
                __syncthreads();
            }
        }
    }
}

// ---- compile-time circuit drivers ----
template<int L, int W>
__device__ __forceinline__ void do_rots(float (&ar)[CHUNK], float (&ai)[CHUNK],
                                        const float* __restrict__ gm, int tid, F4* buf) {
    rot_gate<13-W>(ar, ai, gm + (L*NQ + W)*8, tid, buf);
    if constexpr (W < NQ-1) do_rots<L, W+1>(ar, ai, gm, tid, buf);
}

template<int L, int W>
__device__ __forceinline__ void do_cnots(float (&ar)[CHUNK], float (&ai)[CHUNK],
                                         int tid, F4* buf) {
    constexpr int R = (L % (NQ-1)) + 1;
    constexpr int TW = (W + R) % NQ;
    cnot_gate<13-W, 13-TW>(ar, ai, tid, buf);
    if constexpr (W < NQ-1) do_cnots<L, W+1>(ar, ai, tid, buf);
}

template<int L>
__device__ __forceinline__ void do_layer(float (&ar)[CHUNK], float (&ai)[CHUNK],
                                         const float* __restrict__ gm, int tid, F4* buf) {
    do_rots<L, 0>(ar, ai, gm, tid, buf);
    do_cnots<L, 0>(ar, ai, tid, buf);
    if constexpr (L < NL-1) do_layer<L+1>(ar, ai, gm, tid, buf);
}

__global__ void __launch_bounds__(NT)
qsim_kernel(
    const float* __restrict__ x,
    const float* __restrict__ gm,
    float* __restrict__ out)
{
    __shared__ F4 buf[8 * NT];   // static 64 KB -> compiler sees 2 blocks/CU
    const int tid = threadIdx.x;
    const int b = blockIdx.x;
    const float* xb = x + b * NQ;

    // ---- direct product-state init: state after RX(x_w) on |0..0> ----
    // amp(p) = prod_bits [ bit ? -i*sin(x/2) : cos(x/2) ]
    float ar[CHUNK], ai[CHUNK];
    {
        // thread-common factor over tid bits 0..8 (amp bit 5+bb, wire 8-bb)
        float cr = 1.f, ci = 0.f;
        #pragma unroll
        for (int bb = 0; bb < 9; ++bb) {
            float t = xb[8 - bb];
            float c = cosf(0.5f*t), s = sinf(0.5f*t);
            if ((tid >> bb) & 1) { float nr = s*ci, ni = -s*cr; cr = nr; ci = ni; }
            else                 { cr *= c; ci *= c; }
        }
        // local bits 0..4 (amp bit bb, wire 13-bb)
        float lc[5], ls[5];
        #pragma unroll
        for (int bb = 0; bb < 5; ++bb) {
            float t = xb[13 - bb];
            lc[bb] = cosf(0.5f*t); ls[bb] = sinf(0.5f*t);
        }
        #pragma unroll
        for (int j = 0; j < CHUNK; ++j) {
            float rr = cr, ii = ci;
            #pragma unroll
            for (int bb = 0; bb < 5; ++bb) {
                if ((j >> bb) & 1) { float nr = ls[bb]*ii, ni = -ls[bb]*rr; rr = nr; ii = ni; }
                else               { rr *= lc[bb]; ii *= lc[bb]; }
            }
            ar[j] = rr; ai[j] = ii;
        }
    }
    __syncthreads();

    do_layer<0>(ar, ai, gm, tid, buf);

    // <Z0>: amp bit 13 = tid bit 8 -> sign uniform per thread
    float acc = 0.f;
    #pragma unroll
    for (int j = 0; j < CHUNK; ++j) acc += ar[j]*ar[j] + ai[j]*ai[j];
    if (tid & 256) acc = -acc;
    #pragma unroll
    for (int off = 32; off > 0; off >>= 1) acc += __shfl_down(acc, off, 64);
    __syncthreads();
    float* f = (float*)buf;
    if ((tid & 63) == 0) f[tid >> 6] = acc;
    __syncthreads();
    if (tid == 0) {
        float s = 0.f;
        #pragma unroll
        for (int w = 0; w < NT/64; ++w) s += f[w];
        out[b] = s;
    }
}

extern "C" void kernel_launch(void* const* d_in, const int* in_sizes, int n_in,
                              void* d_out, int out_size, void* d_ws, size_t ws_size,
                              hipStream_t stream) {
    const float* x = (const float*)d_in[0];   // (1024, 14) float32
    const float* w = (const float*)d_in[1];   // (6, 14, 3) float32
    float* out = (float*)d_out;               // (1024,) float32
    float* gm = (float*)d_ws;                 // 84*8 floats of Rot matrices

    prep_kernel<<<1, 128, 0, stream>>>(w, gm);
    qsim_kernel<<<out_size, NT, 0, stream>>>(x, gm, out);
}